// Round 4
// baseline (128.458 us; speedup 1.0000x reference)
//
#include <hip/hip_runtime.h>
#include <hip/hip_bf16.h>
#include <math.h>

// Shapes
#define QL 32768
#define DD 1024
#define NTOK 64

using short8   = __attribute__((ext_vector_type(8))) short;
using f32x4    = __attribute__((ext_vector_type(4))) float;
using float4v  = __attribute__((ext_vector_type(4))) float;
using ushort4v = __attribute__((ext_vector_type(4))) unsigned short;

// RNE f32->bf16 via bit trick (exact RNE)
__device__ __forceinline__ unsigned short f2bf(float f) {
    unsigned int u = __float_as_uint(f);
    unsigned int r = (u + 0x7FFFu + ((u >> 16) & 1u)) >> 16;
    return (unsigned short)r;
}

// ---------------------------------------------------------------------------
// Prologue 1: transpose-convert Wq (1024x1024) -> WqT bf16, Pv (64x1024) -> PvT bf16.
// grid 272 x 256: blocks 0..255 -> Wq tiles, 256..271 -> Pv tiles.
// ---------------------------------------------------------------------------
__global__ __launch_bounds__(256) void prep_transpose_kernel(
        const float* __restrict__ Wq, const float* __restrict__ Pv,
        unsigned short* __restrict__ WqT, unsigned short* __restrict__ PvT) {
    __shared__ float tile[64][65];
    int b = blockIdx.x;
    const float* src; unsigned short* dst; int R, C, r0, c0;
    if (b < 256) { src = Wq; dst = WqT; R = 1024; C = 1024;
                   r0 = (b >> 4) << 6; c0 = (b & 15) << 6; }
    else         { b -= 256; src = Pv; dst = PvT; R = 64; C = 1024;
                   r0 = 0; c0 = b << 6; }
    const int tid = threadIdx.x;
#pragma unroll
    for (int i = 0; i < 16; ++i) {
        const int lin = tid + 256 * i;
        const int row = lin >> 6, col = lin & 63;
        if (r0 + row < R)
            tile[row][col] = src[(size_t)(r0 + row) * C + c0 + col];
    }
    __syncthreads();
    // dst is C x R: dst[c0+row][r0+col] = tile[col][row]
#pragma unroll
    for (int i = 0; i < 16; ++i) {
        const int lin = tid + 256 * i;
        const int row = lin >> 6, col = lin & 63;
        if (r0 + col < R)
            dst[(size_t)(c0 + row) * R + r0 + col] = f2bf(tile[col][row]);
    }
}

// ---------------------------------------------------------------------------
// Prologue 2: Kp = Pk @ Wq via bf16 MFMA (B from WqT). grid 16 x 256.
// ---------------------------------------------------------------------------
__global__ __launch_bounds__(256) void kp_mfma_kernel(
        const float* __restrict__ Pk, const unsigned short* __restrict__ WqT,
        unsigned short* __restrict__ Kp) {
    const int tid = threadIdx.x;
    const int w   = tid >> 6;
    const int l   = tid & 63;
    const int lhi = l >> 4;
    const int llo = l & 15;
    const int N0  = blockIdx.x * 64;

    f32x4 acc[4];
#pragma unroll
    for (int ct = 0; ct < 4; ++ct) acc[ct] = (f32x4){0.f, 0.f, 0.f, 0.f};

    for (int kb = 0; kb < 32; ++kb) {
        const int k0 = kb * 32 + lhi * 8;
        float4v p0 = *(const float4v*)(Pk + (size_t)(w * 16 + llo) * DD + k0);
        float4v p1 = *(const float4v*)(Pk + (size_t)(w * 16 + llo) * DD + k0 + 4);
        short8 a;
        a[0] = (short)f2bf(p0.x); a[1] = (short)f2bf(p0.y);
        a[2] = (short)f2bf(p0.z); a[3] = (short)f2bf(p0.w);
        a[4] = (short)f2bf(p1.x); a[5] = (short)f2bf(p1.y);
        a[6] = (short)f2bf(p1.z); a[7] = (short)f2bf(p1.w);
#pragma unroll
        for (int ct = 0; ct < 4; ++ct) {
            short8 b = *(const short8*)(WqT + (size_t)(N0 + ct * 16 + llo) * DD + k0);
            acc[ct] = __builtin_amdgcn_mfma_f32_16x16x32_bf16(a, b, acc[ct], 0, 0, 0);
        }
    }
#pragma unroll
    for (int ct = 0; ct < 4; ++ct) {
#pragma unroll
        for (int j = 0; j < 4; ++j) {
            const int t = w * 16 + lhi * 4 + j;
            const int d = N0 + ct * 16 + llo;
            Kp[(size_t)t * DD + d] = f2bf(acc[ct][j]);
        }
    }
}

// ---------------------------------------------------------------------------
// Fused: s = x @ Kp^T -> row l2-norm * 8 -> exact GELU -> y = s' @ Pv
// grid 2048 blocks x 256 threads (4 waves). Block owns 16 rows; wave w
// contracts K-quarter [w*256, w*256+256) with 16-deep batched global loads.
// GEMM2 computes D[m=d][n=q] (swapped operands) -> float4 row stores.
// ---------------------------------------------------------------------------
__global__ __launch_bounds__(256, 4) void fused_kernel(
        const float* __restrict__ x, const unsigned short* __restrict__ Kp,
        const unsigned short* __restrict__ PvT, float* __restrict__ out) {
    __shared__ float sPart[4][16][68];                    // stride 68: bank-shifted rows
    __shared__ __align__(16) unsigned char sS[16 * 128];  // s' bf16 [16][64] swizzled

    const int tid = threadIdx.x;
    const int w   = tid >> 6;
    const int l   = tid & 63;
    const int lhi = l >> 4;    // 0..3
    const int llo = l & 15;    // 0..15
    const int R0  = blockIdx.x * 16;
    const int K0  = w * 256;   // this wave's K-quarter

    f32x4 acc[4];
#pragma unroll
    for (int ct = 0; ct < 4; ++ct) acc[ct] = (f32x4){0.f, 0.f, 0.f, 0.f};

    const float*          xrow = x  + (size_t)(R0 + llo) * DD + K0 + lhi * 8;
    const unsigned short* kpr  = Kp + (size_t)llo * DD + K0 + lhi * 8;

    // ---- batch ALL x loads for this wave's K-quarter (16 outstanding) ----
    float4v xq[16];
#pragma unroll
    for (int ks = 0; ks < 8; ++ks) {
        xq[2 * ks]     = *(const float4v*)(xrow + ks * 32);
        xq[2 * ks + 1] = *(const float4v*)(xrow + ks * 32 + 4);
    }

    // ---- GEMM1 (K-quarter): cvt + MFMA ----
#pragma unroll
    for (int ks = 0; ks < 8; ++ks) {
        short8 a;
        a[0] = (short)f2bf(xq[2 * ks].x); a[1] = (short)f2bf(xq[2 * ks].y);
        a[2] = (short)f2bf(xq[2 * ks].z); a[3] = (short)f2bf(xq[2 * ks].w);
        a[4] = (short)f2bf(xq[2 * ks + 1].x); a[5] = (short)f2bf(xq[2 * ks + 1].y);
        a[6] = (short)f2bf(xq[2 * ks + 1].z); a[7] = (short)f2bf(xq[2 * ks + 1].w);
#pragma unroll
        for (int ct = 0; ct < 4; ++ct) {
            short8 b = *(const short8*)(kpr + (size_t)ct * 16 * DD + ks * 32);
            acc[ct] = __builtin_amdgcn_mfma_f32_16x16x32_bf16(a, b, acc[ct], 0, 0, 0);
        }
    }

    // partials -> LDS (row = lhi*4+j, col = ct*16+llo)
#pragma unroll
    for (int ct = 0; ct < 4; ++ct)
#pragma unroll
        for (int j = 0; j < 4; ++j)
            sPart[w][lhi * 4 + j][ct * 16 + llo] = acc[ct][j];
    __syncthreads();

    // ---- reduce across waves + row l2-norm*8 + exact GELU -> sS (bf16) ----
    {
        const int r  = tid >> 4;          // 0..15
        const int cb = (tid & 15) * 4;    // 0..60
        f32x4 v  = *(const f32x4*)&sPart[0][r][cb];
        f32x4 v1 = *(const f32x4*)&sPart[1][r][cb];
        f32x4 v2 = *(const f32x4*)&sPart[2][r][cb];
        f32x4 v3 = *(const f32x4*)&sPart[3][r][cb];
        v = v + v1 + v2 + v3;
        float ssq = v.x * v.x + v.y * v.y + v.z * v.z + v.w * v.w;
        ssq += __shfl_xor(ssq, 1);
        ssq += __shfl_xor(ssq, 2);
        ssq += __shfl_xor(ssq, 4);
        ssq += __shfl_xor(ssq, 8);
        const float scale = 8.0f / sqrtf(ssq);
        ushort4v g;
#pragma unroll
        for (int k = 0; k < 4; ++k) {
            const float vv = v[k] * scale;
            const float ge = 0.5f * vv * (1.0f + erff(vv * 0.70710678118654752f));
            g[k] = f2bf(ge);
        }
        *(ushort4v*)(sS + ((r * 128 + cb * 2) ^ ((r & 7) << 4))) = g;
    }
    __syncthreads();

    // ---- GEMM2 (swapped): D[m=d][n=q] = PvT-frag(A) x s'-frag(B) ----
    // B[k=token][n=q]: lane needs s'[q=llo][token = lhi*8..], same bytes as before.
    short8 sb0 = *(const short8*)(sS + ((llo * 128 + lhi * 16)      ^ ((llo & 7) << 4)));
    short8 sb1 = *(const short8*)(sS + ((llo * 128 + 64 + lhi * 16) ^ ((llo & 7) << 4)));

    const int N0w = w * 256;
    float* orow = out + (size_t)(R0 + llo) * DD + N0w + lhi * 4;
#pragma unroll 4
    for (int dt = 0; dt < 16; ++dt) {
        // A[m=d][k=token]: PvT row N0w + dt*16 + llo, tokens lhi*8.. (+32)
        const unsigned short* ap = PvT + (size_t)(N0w + dt * 16 + llo) * 64 + lhi * 8;
        short8 pa0 = *(const short8*)ap;
        short8 pa1 = *(const short8*)(ap + 32);
        f32x4 acc2 = (f32x4){0.f, 0.f, 0.f, 0.f};
        acc2 = __builtin_amdgcn_mfma_f32_16x16x32_bf16(pa0, sb0, acc2, 0, 0, 0);
        acc2 = __builtin_amdgcn_mfma_f32_16x16x32_bf16(pa1, sb1, acc2, 0, 0, 0);
        // lane holds y[q=llo][d = N0w + dt*16 + lhi*4 + j], j=0..3 contiguous
        *(float4v*)(orow + dt * 16) = acc2;
    }
}

// ---------------------------------------------------------------------------
extern "C" void kernel_launch(void* const* d_in, const int* in_sizes, int n_in,
                              void* d_out, int out_size, void* d_ws, size_t ws_size,
                              hipStream_t stream) {
    (void)in_sizes; (void)n_in; (void)out_size; (void)ws_size;
    const float* x  = (const float*)d_in[0];
    const float* Wq = (const float*)d_in[1];
    const float* Pk = (const float*)d_in[2];
    const float* Pv = (const float*)d_in[3];
    float* out = (float*)d_out;

    // ws layout (2.25 MB total):
    //   WqT bf16 [1024][1024] @ 0          (2 MB)
    //   Kp  bf16 [64][1024]   @ 2 MB       (128 KB)
    //   PvT bf16 [1024][64]   @ 2 MB+128K  (128 KB)
    unsigned short* WqT = (unsigned short*)d_ws;
    unsigned short* Kp  = (unsigned short*)((char*)d_ws + 2097152);
    unsigned short* PvT = (unsigned short*)((char*)d_ws + 2097152 + 131072);

    prep_transpose_kernel<<<272, 256, 0, stream>>>(Wq, Pv, WqT, PvT);
    kp_mfma_kernel<<<16, 256, 0, stream>>>(Pk, WqT, Kp);
    fused_kernel<<<2048, 256, 0, stream>>>(x, Kp, PvT, out);
}

// Round 5
// 122.112 us; speedup vs baseline: 1.0520x; 1.0520x over previous
//
#include <hip/hip_runtime.h>
#include <hip/hip_bf16.h>
#include <math.h>

// Shapes
#define QL 32768
#define DD 1024
#define NTOK 64

using short8   = __attribute__((ext_vector_type(8))) short;
using f32x4    = __attribute__((ext_vector_type(4))) float;
using float4v  = __attribute__((ext_vector_type(4))) float;
using ushort4v = __attribute__((ext_vector_type(4))) unsigned short;
using ushort8v = __attribute__((ext_vector_type(8))) unsigned short;
using uint2v   = __attribute__((ext_vector_type(2))) unsigned int;

// RNE f32->bf16 via bit trick (exact RNE)
__device__ __forceinline__ unsigned short f2bf(float f) {
    unsigned int u = __float_as_uint(f);
    unsigned int r = (u + 0x7FFFu + ((u >> 16) & 1u)) >> 16;
    return (unsigned short)r;
}

// ---------------------------------------------------------------------------
// Prologue 1: transpose-convert Wq (1024x1024) -> WqT bf16, Pv (64x1024) -> PvT bf16.
// ---------------------------------------------------------------------------
__global__ __launch_bounds__(256) void prep_transpose_kernel(
        const float* __restrict__ Wq, const float* __restrict__ Pv,
        unsigned short* __restrict__ WqT, unsigned short* __restrict__ PvT) {
    __shared__ float tile[64][65];
    int b = blockIdx.x;
    const float* src; unsigned short* dst; int R, C, r0, c0;
    if (b < 256) { src = Wq; dst = WqT; R = 1024; C = 1024;
                   r0 = (b >> 4) << 6; c0 = (b & 15) << 6; }
    else         { b -= 256; src = Pv; dst = PvT; R = 64; C = 1024;
                   r0 = 0; c0 = b << 6; }
    const int tid = threadIdx.x;
#pragma unroll
    for (int i = 0; i < 16; ++i) {
        const int lin = tid + 256 * i;
        const int row = lin >> 6, col = lin & 63;
        if (r0 + row < R)
            tile[row][col] = src[(size_t)(r0 + row) * C + c0 + col];
    }
    __syncthreads();
#pragma unroll
    for (int i = 0; i < 16; ++i) {
        const int lin = tid + 256 * i;
        const int row = lin >> 6, col = lin & 63;
        if (r0 + col < R)
            dst[(size_t)(c0 + row) * R + r0 + col] = f2bf(tile[col][row]);
    }
}

// ---------------------------------------------------------------------------
// Prologue 2: Kp = Pk @ Wq via bf16 MFMA (B from WqT). grid 16 x 256.
// ---------------------------------------------------------------------------
__global__ __launch_bounds__(256) void kp_mfma_kernel(
        const float* __restrict__ Pk, const unsigned short* __restrict__ WqT,
        unsigned short* __restrict__ Kp) {
    const int tid = threadIdx.x;
    const int w   = tid >> 6;
    const int l   = tid & 63;
    const int lhi = l >> 4;
    const int llo = l & 15;
    const int N0  = blockIdx.x * 64;

    f32x4 acc[4];
#pragma unroll
    for (int ct = 0; ct < 4; ++ct) acc[ct] = (f32x4){0.f, 0.f, 0.f, 0.f};

    for (int kb = 0; kb < 32; ++kb) {
        const int k0 = kb * 32 + lhi * 8;
        float4v p0 = *(const float4v*)(Pk + (size_t)(w * 16 + llo) * DD + k0);
        float4v p1 = *(const float4v*)(Pk + (size_t)(w * 16 + llo) * DD + k0 + 4);
        short8 a;
        a[0] = (short)f2bf(p0.x); a[1] = (short)f2bf(p0.y);
        a[2] = (short)f2bf(p0.z); a[3] = (short)f2bf(p0.w);
        a[4] = (short)f2bf(p1.x); a[5] = (short)f2bf(p1.y);
        a[6] = (short)f2bf(p1.z); a[7] = (short)f2bf(p1.w);
#pragma unroll
        for (int ct = 0; ct < 4; ++ct) {
            short8 b = *(const short8*)(WqT + (size_t)(N0 + ct * 16 + llo) * DD + k0);
            acc[ct] = __builtin_amdgcn_mfma_f32_16x16x32_bf16(a, b, acc[ct], 0, 0, 0);
        }
    }
#pragma unroll
    for (int ct = 0; ct < 4; ++ct) {
#pragma unroll
        for (int j = 0; j < 4; ++j) {
            const int t = w * 16 + lhi * 4 + j;
            const int d = N0 + ct * 16 + llo;
            Kp[(size_t)t * DD + d] = f2bf(acc[ct][j]);
        }
    }
}

// ---------------------------------------------------------------------------
// GEMM1: s' = gelu(l2norm_scale(x @ Kp^T)) as bf16 [32768][64].
// grid 2048 x 64 threads = ONE wave per block, 16 q-rows, all 64 tokens.
// Zero barriers. Double-buffered reg->LDS staging with T14 overlap:
// issue next tile's coalesced loads BEFORE compute, ds_write after.
// LDS tile bf16 [16][128] XOR-swizzled (^((r&7)<<4)).
// ---------------------------------------------------------------------------
__global__ __launch_bounds__(64, 4) void gemm1_kernel(
        const float* __restrict__ x, const unsigned short* __restrict__ Kp,
        unsigned short* __restrict__ sp) {
    __shared__ __align__(16) unsigned char sX[2][4096];

    const int l   = threadIdx.x;      // 0..63
    const int lhi = l >> 4;           // 0..3
    const int llo = l & 15;           // 0..15
    const int R0  = blockIdx.x * 16;

    f32x4 acc[4];
#pragma unroll
    for (int ct = 0; ct < 4; ++ct) acc[ct] = (f32x4){0.f, 0.f, 0.f, 0.f};

    float4v xr[8];
    const char* xbase = (const char*)x + (size_t)R0 * 4096;

    // load tile kk (16 rows x 128 f32 = 8KB) into regs, perfectly coalesced:
    // instr i covers rows {2i, 2i+1}: lane byte flat = i*1024 + l*16.
#define LOADT(kk)                                                              \
    {                                                                          \
        const char* xb = xbase + (kk) * 512;                                   \
        _Pragma("unroll")                                                      \
        for (int i = 0; i < 8; ++i) {                                          \
            const int flat = i * 1024 + l * 16;                                \
            const int r    = flat >> 9;                                        \
            const int c    = flat & 511;                                       \
            xr[i] = *(const float4v*)(xb + (size_t)r * 4096 + c);              \
        }                                                                      \
    }

    // cvt f32->bf16 (v_cvt_pk) and write to LDS buf (8B stores, swizzled)
#define WRITET(buf)                                                            \
    {                                                                          \
        _Pragma("unroll")                                                      \
        for (int i = 0; i < 8; ++i) {                                          \
            const int flat = i * 1024 + l * 16;                                \
            const int r    = flat >> 9;                                        \
            const int cb   = (flat & 511) >> 1;                                \
            __hip_bfloat162 h01 = __float22bfloat162_rn(float2{xr[i].x, xr[i].y}); \
            __hip_bfloat162 h23 = __float22bfloat162_rn(float2{xr[i].z, xr[i].w}); \
            uint2v u;                                                          \
            u.x = *(unsigned int*)&h01;                                        \
            u.y = *(unsigned int*)&h23;                                        \
            const int o = (r * 256 + cb) ^ ((r & 7) << 4);                     \
            *(uint2v*)(sX[buf] + o) = u;                                       \
        }                                                                      \
    }

    LOADT(0);
    WRITET(0);

#pragma unroll
    for (int kk = 0; kk < 8; ++kk) {
        if (kk < 7) LOADT(kk + 1);                    // loads in flight...
        // ---- compute tile kk (reads overlap the in-flight loads) ----
        const int buf = kk & 1;
#pragma unroll
        for (int ks = 0; ks < 4; ++ks) {
            short8 a = *(const short8*)(sX[buf] +
                         ((llo * 256 + ks * 64 + lhi * 16) ^ ((llo & 7) << 4)));
#pragma unroll
            for (int ct = 0; ct < 4; ++ct) {
                short8 b = *(const short8*)(Kp + (size_t)(ct * 16 + llo) * DD
                                            + kk * 128 + ks * 32 + lhi * 8);
                acc[ct] = __builtin_amdgcn_mfma_f32_16x16x32_bf16(a, b, acc[ct], 0, 0, 0);
            }
        }
        if (kk < 7) WRITET((kk + 1) & 1);             // ...drained here
    }
#undef LOADT
#undef WRITET

    // ---- in-wave row l2-norm*8 + exact GELU -> sp (bf16) ----
    // acc[ct][j] = s[q = lhi*4+j][t = ct*16+llo]
#pragma unroll
    for (int j = 0; j < 4; ++j) {
        float ssq = 0.f;
#pragma unroll
        for (int ct = 0; ct < 4; ++ct) ssq += acc[ct][j] * acc[ct][j];
        ssq += __shfl_xor(ssq, 1);
        ssq += __shfl_xor(ssq, 2);
        ssq += __shfl_xor(ssq, 4);
        ssq += __shfl_xor(ssq, 8);
        const float scale = 8.0f / sqrtf(ssq);
        const int q = R0 + lhi * 4 + j;
#pragma unroll
        for (int ct = 0; ct < 4; ++ct) {
            const float v = acc[ct][j] * scale;
            const float g = 0.5f * v * (1.0f + erff(v * 0.70710678118654752f));
            sp[(size_t)q * 64 + ct * 16 + llo] = f2bf(g);
        }
    }
}

// ---------------------------------------------------------------------------
// GEMM2: y[32768][1024] = s'(bf16) @ Pv, swapped MFMA (D[m=d][n=q]),
// float4 stores. grid 2048 x 256 (4 waves); block = 16 q-rows; wave = 256 d-cols.
// ---------------------------------------------------------------------------
__global__ __launch_bounds__(256, 4) void gemm2_kernel(
        const unsigned short* __restrict__ sp, const unsigned short* __restrict__ PvT,
        float* __restrict__ out) {
    __shared__ __align__(16) unsigned char sS[16 * 128];  // s' [16][64] bf16 swizzled

    const int tid = threadIdx.x;
    const int w   = tid >> 6;
    const int l   = tid & 63;
    const int lhi = l >> 4;
    const int llo = l & 15;
    const int R0  = blockIdx.x * 16;

    // stage s' tile (2KB) coalesced, swizzled
    if (tid < 128) {
        const int o = tid * 16;             // flat byte in [16][128]
        const int q = o >> 7;
        ushort8v v = *(const ushort8v*)(sp + (size_t)R0 * 64 + tid * 8);
        *(ushort8v*)(sS + (o ^ ((q & 7) << 4))) = v;
    }
    __syncthreads();

    short8 sb0 = *(const short8*)(sS + ((llo * 128 + lhi * 16)      ^ ((llo & 7) << 4)));
    short8 sb1 = *(const short8*)(sS + ((llo * 128 + 64 + lhi * 16) ^ ((llo & 7) << 4)));

    const int N0w = w * 256;
    float* orow = out + (size_t)(R0 + llo) * DD + N0w + lhi * 4;
#pragma unroll 4
    for (int dt = 0; dt < 16; ++dt) {
        const unsigned short* ap = PvT + (size_t)(N0w + dt * 16 + llo) * 64 + lhi * 8;
        short8 pa0 = *(const short8*)ap;
        short8 pa1 = *(const short8*)(ap + 32);
        f32x4 acc2 = (f32x4){0.f, 0.f, 0.f, 0.f};
        acc2 = __builtin_amdgcn_mfma_f32_16x16x32_bf16(pa0, sb0, acc2, 0, 0, 0);
        acc2 = __builtin_amdgcn_mfma_f32_16x16x32_bf16(pa1, sb1, acc2, 0, 0, 0);
        *(float4v*)(orow + dt * 16) = acc2;
    }
}

// ---------------------------------------------------------------------------
extern "C" void kernel_launch(void* const* d_in, const int* in_sizes, int n_in,
                              void* d_out, int out_size, void* d_ws, size_t ws_size,
                              hipStream_t stream) {
    (void)in_sizes; (void)n_in; (void)out_size; (void)ws_size;
    const float* x  = (const float*)d_in[0];
    const float* Wq = (const float*)d_in[1];
    const float* Pk = (const float*)d_in[2];
    const float* Pv = (const float*)d_in[3];
    float* out = (float*)d_out;

    // ws layout (6.25 MB total):
    //   WqT bf16 [1024][1024] @ 0            (2 MB)
    //   Kp  bf16 [64][1024]   @ 2 MB         (128 KB)
    //   PvT bf16 [1024][64]   @ 2 MB + 128K  (128 KB)
    //   s'  bf16 [32768][64]  @ 2.25 MB      (4 MB)
    unsigned short* WqT = (unsigned short*)d_ws;
    unsigned short* Kp  = (unsigned short*)((char*)d_ws + 2097152);
    unsigned short* PvT = (unsigned short*)((char*)d_ws + 2097152 + 131072);
    unsigned short* sp  = (unsigned short*)((char*)d_ws + 2097152 + 262144);

    prep_transpose_kernel<<<272, 256, 0, stream>>>(Wq, Pv, WqT, PvT);
    kp_mfma_kernel<<<16, 256, 0, stream>>>(Pk, WqT, Kp);
    gemm1_kernel<<<2048, 64, 0, stream>>>(x, Kp, sp);
    gemm2_kernel<<<2048, 256, 0, stream>>>(sp, PvT, out);
}